// Round 19
// baseline (336.666 us; speedup 1.0000x reference)
//
#include <hip/hip_runtime.h>

// LSTM T=1024, B=2048, INPUT=2, H=64 — MFMA recurrence.
// R18 = R17 (antiphase twin blocks BB=4/512, 1-state/lane, zero-C MFMA,
// paired rcp, pre-scaled log2e gx, lds_barrier, setprio(1) act phase,
// 512-cyc skew, manual 4x unroll with static parity + named x0..x3)
// + regime-gated retry of R14's two issue cuts (now that R17 measures 86%
// VALU-issue-bound; in R14 the kernel was chain-bound and they couldn't pay):
//  1. packed gxL: f32x2 constants + elementwise_fma -> 4 v_pk_fma_f32.
//  2. native __bf16 store -> v_cvt_pk_bf16_f32 (RNE, bit-identical).
// Numerics identical (bf16 W_hh, bf16 h, fp32 c, absmax 4.88e-4).

typedef short bf16x8 __attribute__((ext_vector_type(8)));
typedef float f32x4  __attribute__((ext_vector_type(4)));
typedef float f32x2  __attribute__((ext_vector_type(2)));

constexpr int T_STEPS = 1024;
constexpr int BATCH   = 2048;
constexpr int H       = 64;
constexpr int BB      = 4;      // batch per block
constexpr int THREADS = 256;    // 4 waves
constexpr int HSTR    = 80;     // bf16 per batch row (160 B = 40 dwords)

__device__ __forceinline__ unsigned bf16_rn(float f) {
    unsigned u = __float_as_uint(f);
    u += 0x7fffu + ((u >> 16) & 1u);
    return u >> 16;
}
__device__ __forceinline__ float rcp_(float v)  { return __builtin_amdgcn_rcpf(v); }
__device__ __forceinline__ float exp2_(float v) { return __builtin_amdgcn_exp2f(v); }
// barrier that does NOT drain vmcnt (keeps x prefetch in flight)
__device__ __forceinline__ void lds_barrier() {
    asm volatile("s_waitcnt lgkmcnt(0)" ::: "memory");
    __builtin_amdgcn_s_barrier();
}

__global__ __launch_bounds__(THREADS, 2) void lstm_mfma18(
    const float* __restrict__ x,      // (T, B, 2)
    const float* __restrict__ W_ih,   // (256, 2)
    const float* __restrict__ W_hh,   // (256, 64)
    const float* __restrict__ b_ih,   // (256)
    const float* __restrict__ b_hh,   // (256)
    const float* __restrict__ W_fc,   // (1, 64)
    const float* __restrict__ b_fc,   // (1)
    float* __restrict__ out)          // (B, 1)
{
    const int tid  = threadIdx.x;
    const int w    = tid >> 6;        // wave 0..3: h-slice [16w, 16w+16)
    const int lane = tid & 63;
    const int bcol = lane & 15;       // MFMA column
    const int grp  = lane >> 4;       // k-group / D-row group
    const int bloc = bcol & 3;        // real batch (cols 4..15 dup 0..3)
    const int eh   = bcol >> 2;       // which D element this lane activates

    __shared__ __align__(16) unsigned short s_ht[2][BB * HSTR]; // 2 x 640 B
    __shared__ float s_red[16];

    const int b0 = blockIdx.x * BB;

    constexpr float L1 = -1.44269504f;   // -log2(e)
    constexpr float L2 =  2.88539008f;   //  2 log2(e)

    // ---- A fragments: gate g tile = W_hh rows [64g+16w, +16), single bf16 -
    bf16x8 Af[4][2];
    #pragma unroll
    for (int g = 0; g < 4; ++g) {
        #pragma unroll
        for (int kk = 0; kk < 2; ++kk) {
            const float* src = W_hh + (64 * g + 16 * w + bcol) * H + kk * 32 + grp * 8;
            #pragma unroll
            for (int j = 0; j < 8; ++j)
                Af[g][kk][j] = (short)bf16_rn(src[j]);
        }
    }

    // ---- per-lane single state: h-row rbase of batch b0+bloc --------------
    const int rbase = 16 * w + 4 * grp + eh;
    float cs = 0.f, hv = 0.f;
    const float wfc = W_fc[rbase];

    // ---- gx constants for the 4 used rows, PRE-SCALED by Lg, as f32x2 -----
    f32x2 gbL01, gbL23, c0L01, c0L23, c1L01, c1L23;
    {
        float gbL[4], c0L[4], c1L[4];
        #pragma unroll
        for (int g = 0; g < 4; ++g) {
            const int r = 64 * g + rbase;
            const float Lg = (g == 2) ? L2 : L1;
            gbL[g] = (b_ih[r] + b_hh[r]) * Lg;
            c0L[g] = W_ih[2 * r] * Lg;
            c1L[g] = W_ih[2 * r + 1] * Lg;
        }
        gbL01 = f32x2{gbL[0], gbL[1]}; gbL23 = f32x2{gbL[2], gbL[3]};
        c0L01 = f32x2{c0L[0], c0L[1]}; c0L23 = f32x2{c0L[2], c0L[3]};
        c1L01 = f32x2{c1L[0], c1L[1]}; c1L23 = f32x2{c1L[2], c1L[3]};
    }

    // hoisted zero C for the first MFMA of each chain
    const f32x4 zero4 = {0.f, 0.f, 0.f, 0.f};

    // zero both h-table buffers (2*4*80 shorts = 320 dwords)
    for (int i = tid; i < 320; i += THREADS)
        reinterpret_cast<unsigned*>(s_ht)[i] = 0;

    // ---- x: depth-4 prefetch in four NAMED regs (static rotation) ---------
    const float* xb = x + (b0 + bloc) * 2;
    float2 x0 = *reinterpret_cast<const float2*>(xb + 0 * BATCH * 2);
    float2 x1 = *reinterpret_cast<const float2*>(xb + 1 * BATCH * 2);
    float2 x2 = *reinterpret_cast<const float2*>(xb + 2 * BATCH * 2);
    float2 x3 = *reinterpret_cast<const float2*>(xb + 3 * BATCH * 2);

    __syncthreads();   // one full barrier (init visible)

    // ---- ANTIPHASE SKEW: second dispatch wave spins ~512 cyc once ---------
    if (blockIdx.x & 256) {
        asm volatile(
            "s_nop 7\n s_nop 7\n s_nop 7\n s_nop 7\n s_nop 7\n s_nop 7\n s_nop 7\n s_nop 7\n"
            "s_nop 7\n s_nop 7\n s_nop 7\n s_nop 7\n s_nop 7\n s_nop 7\n s_nop 7\n s_nop 7\n"
            "s_nop 7\n s_nop 7\n s_nop 7\n s_nop 7\n s_nop 7\n s_nop 7\n s_nop 7\n s_nop 7\n"
            "s_nop 7\n s_nop 7\n s_nop 7\n s_nop 7\n s_nop 7\n s_nop 7\n s_nop 7\n s_nop 7\n"
            "s_nop 7\n s_nop 7\n s_nop 7\n s_nop 7\n s_nop 7\n s_nop 7\n s_nop 7\n s_nop 7\n"
            "s_nop 7\n s_nop 7\n s_nop 7\n s_nop 7\n s_nop 7\n s_nop 7\n s_nop 7\n s_nop 7\n"
            "s_nop 7\n s_nop 7\n s_nop 7\n s_nop 7\n s_nop 7\n s_nop 7\n s_nop 7\n s_nop 7\n"
            "s_nop 7\n s_nop 7\n s_nop 7\n s_nop 7\n s_nop 7\n s_nop 7\n s_nop 7\n s_nop 7\n"
            ::: "memory");
    }

    // initial B fragments from buf 0 (h = 0); single b128 per kk
    bf16x8 Bf[2];
    #pragma unroll
    for (int kk = 0; kk < 2; ++kk)
        Bf[kk] = *reinterpret_cast<const bf16x8*>(
                     &s_ht[0][bloc * HSTR + kk * 32 + grp * 8]);

    // one LSTM step; XV = this sub-step's x slot (consumed then reloaded
    // with the value 4 steps ahead); P = compile-time h-table parity.
#define LSTM_STEP(XV, P, SN)                                                   \
    {                                                                          \
        const f32x2 xx = {(XV).x, (XV).x};                                     \
        const f32x2 yy = {(XV).y, (XV).y};                                     \
        const f32x2 gx01 = __builtin_elementwise_fma(                          \
            c1L01, yy, __builtin_elementwise_fma(c0L01, xx, gbL01));           \
        const f32x2 gx23 = __builtin_elementwise_fma(                          \
            c1L23, yy, __builtin_elementwise_fma(c0L23, xx, gbL23));           \
        const float gxL[4] = {gx01.x, gx01.y, gx23.x, gx23.y};                 \
        const int sn_ = ((SN) < T_STEPS) ? (SN) : T_STEPS - 1;                 \
        (XV) = *reinterpret_cast<const float2*>(xb + sn_ * BATCH * 2);         \
        f32x4 acc[4];                                                          \
        _Pragma("unroll")                                                      \
        for (int g = 0; g < 4; ++g)                                            \
            acc[g] = __builtin_amdgcn_mfma_f32_16x16x32_bf16(                  \
                         Af[g][0], Bf[0], zero4, 0, 0, 0);                     \
        _Pragma("unroll")                                                      \
        for (int g = 0; g < 4; ++g)                                            \
            acc[g] = __builtin_amdgcn_mfma_f32_16x16x32_bf16(                  \
                         Af[g][1], Bf[1], acc[g], 0, 0, 0);                    \
        __builtin_amdgcn_s_setprio(1);                                         \
        float pL[4];                                                           \
        _Pragma("unroll")                                                      \
        for (int g = 0; g < 4; ++g) {                                          \
            const float v01 = (eh & 1) ? acc[g][1] : acc[g][0];                \
            const float v23 = (eh & 1) ? acc[g][3] : acc[g][2];                \
            const float sel = (eh & 2) ? v23 : v01;                            \
            pL[g] = fmaf(sel, (g == 2) ? L2 : L1, gxL[g]);                     \
        }                                                                      \
        {                                                                      \
            const float ei = exp2_(pL[0]), ef = exp2_(pL[1]);                  \
            const float eg = exp2_(pL[2]), eo = exp2_(pL[3]);                  \
            const float ai = 1.f + ei, af = 1.f + ef;                          \
            const float ag = 1.f + eg, ao = 1.f + eo;                          \
            const float rif = rcp_(ai * af);                                   \
            const float si = rif * af, sf = rif * ai;                          \
            const float rgo = rcp_(ag * ao);                                   \
            const float tg = fmaf(-2.f, rgo * ao, 1.f);                        \
            const float so = rgo * ag;                                         \
            cs = fmaf(sf, cs, si * tg);                                        \
            const float ec = exp2_(cs * L2);                                   \
            hv = so * fmaf(-2.f, rcp_(1.f + ec), 1.f);                         \
        }                                                                      \
        *reinterpret_cast<__bf16*>(&s_ht[P][bloc * HSTR + rbase]) = (__bf16)hv;\
        __builtin_amdgcn_s_setprio(0);                                         \
        lds_barrier();                                                         \
        _Pragma("unroll")                                                      \
        for (int kk = 0; kk < 2; ++kk)                                         \
            Bf[kk] = *reinterpret_cast<const bf16x8*>(                         \
                         &s_ht[P][bloc * HSTR + kk * 32 + grp * 8]);           \
    }

    for (int s = 0; s < T_STEPS; s += 4) {
        LSTM_STEP(x0, 1, s + 4);
        LSTM_STEP(x1, 0, s + 5);
        LSTM_STEP(x2, 1, s + 6);
        LSTM_STEP(x3, 0, s + 7);
    }
#undef LSTM_STEP

    // ---- fused fc epilogue ----------------------------------------------
    float v = hv * wfc;
    v += __shfl_xor(v, 4);    // eh bit 0
    v += __shfl_xor(v, 8);    // eh bit 1
    v += __shfl_xor(v, 16);   // grp bit 0
    v += __shfl_xor(v, 32);   // grp bit 1
    if (lane < 4) s_red[w * 4 + lane] = v;   // one writer per (w, bloc)
    __syncthreads();
    if (tid < 4) {
        out[b0 + tid] = s_red[tid] + s_red[4 + tid] + s_red[8 + tid]
                      + s_red[12 + tid] + b_fc[0];
    }
}

extern "C" void kernel_launch(void* const* d_in, const int* in_sizes, int n_in,
                              void* d_out, int out_size, void* d_ws, size_t ws_size,
                              hipStream_t stream) {
    const float* x    = (const float*)d_in[0];
    const float* W_ih = (const float*)d_in[1];
    const float* W_hh = (const float*)d_in[2];
    const float* b_ih = (const float*)d_in[3];
    const float* b_hh = (const float*)d_in[4];
    const float* W_fc = (const float*)d_in[5];
    const float* b_fc = (const float*)d_in[6];
    float* out = (float*)d_out;

    dim3 grid(BATCH / BB);   // 512 blocks -> 2 independent blocks per CU
    dim3 block(THREADS);     // 4 waves
    lstm_mfma18<<<grid, block, 0, stream>>>(x, W_ih, W_hh, b_ih, b_hh, W_fc, b_fc, out);
}

// Round 20
// 299.101 us; speedup vs baseline: 1.1256x; 1.1256x over previous
//
#include <hip/hip_runtime.h>

// LSTM T=1024, B=2048, INPUT=2, H=64 — MFMA recurrence.
// R19 = R17 EXACTLY (measured best: 299.5 us scoring / ~345 steady).
// Antiphase twin blocks BB=4/512 blocks (2 independent blocks/CU),
// 1-state/lane, zero-C MFMA, paired rcp, pre-scaled log2e gx, lds_barrier,
// setprio(1) act phase, 512-cyc skew, manual 4x unroll (static parity,
// named x0..x3 depth-4 prefetch). R14/R18 both showed packed-fma + __bf16
// cast REGRESS in either regime (scheduling/pack exposure) — rejected.
// Numerics: bf16 W_hh, fresh-rounded bf16 h, fp32 c (absmax 4.88e-4).

typedef short bf16x8 __attribute__((ext_vector_type(8)));
typedef float f32x4  __attribute__((ext_vector_type(4)));

constexpr int T_STEPS = 1024;
constexpr int BATCH   = 2048;
constexpr int H       = 64;
constexpr int BB      = 4;      // batch per block
constexpr int THREADS = 256;    // 4 waves
constexpr int HSTR    = 80;     // bf16 per batch row (160 B = 40 dwords)

__device__ __forceinline__ unsigned bf16_rn(float f) {
    unsigned u = __float_as_uint(f);
    u += 0x7fffu + ((u >> 16) & 1u);
    return u >> 16;
}
__device__ __forceinline__ float rcp_(float v)  { return __builtin_amdgcn_rcpf(v); }
__device__ __forceinline__ float exp2_(float v) { return __builtin_amdgcn_exp2f(v); }
// barrier that does NOT drain vmcnt (keeps x prefetch in flight)
__device__ __forceinline__ void lds_barrier() {
    asm volatile("s_waitcnt lgkmcnt(0)" ::: "memory");
    __builtin_amdgcn_s_barrier();
}

__global__ __launch_bounds__(THREADS, 2) void lstm_mfma19(
    const float* __restrict__ x,      // (T, B, 2)
    const float* __restrict__ W_ih,   // (256, 2)
    const float* __restrict__ W_hh,   // (256, 64)
    const float* __restrict__ b_ih,   // (256)
    const float* __restrict__ b_hh,   // (256)
    const float* __restrict__ W_fc,   // (1, 64)
    const float* __restrict__ b_fc,   // (1)
    float* __restrict__ out)          // (B, 1)
{
    const int tid  = threadIdx.x;
    const int w    = tid >> 6;        // wave 0..3: h-slice [16w, 16w+16)
    const int lane = tid & 63;
    const int bcol = lane & 15;       // MFMA column
    const int grp  = lane >> 4;       // k-group / D-row group
    const int bloc = bcol & 3;        // real batch (cols 4..15 dup 0..3)
    const int eh   = bcol >> 2;       // which D element this lane activates

    __shared__ __align__(16) unsigned short s_ht[2][BB * HSTR]; // 2 x 640 B
    __shared__ float s_red[16];

    const int b0 = blockIdx.x * BB;

    constexpr float L1 = -1.44269504f;   // -log2(e)
    constexpr float L2 =  2.88539008f;   //  2 log2(e)

    // ---- A fragments: gate g tile = W_hh rows [64g+16w, +16), single bf16 -
    bf16x8 Af[4][2];
    #pragma unroll
    for (int g = 0; g < 4; ++g) {
        #pragma unroll
        for (int kk = 0; kk < 2; ++kk) {
            const float* src = W_hh + (64 * g + 16 * w + bcol) * H + kk * 32 + grp * 8;
            #pragma unroll
            for (int j = 0; j < 8; ++j)
                Af[g][kk][j] = (short)bf16_rn(src[j]);
        }
    }

    // ---- per-lane single state: h-row rbase of batch b0+bloc --------------
    const int rbase = 16 * w + 4 * grp + eh;
    float cs = 0.f, hv = 0.f;
    const float wfc = W_fc[rbase];

    // ---- gx constants for the 4 used rows, PRE-SCALED by Lg ---------------
    float gbL[4], c0L[4], c1L[4];
    #pragma unroll
    for (int g = 0; g < 4; ++g) {
        const int r = 64 * g + rbase;
        const float Lg = (g == 2) ? L2 : L1;
        gbL[g] = (b_ih[r] + b_hh[r]) * Lg;
        c0L[g] = W_ih[2 * r] * Lg;
        c1L[g] = W_ih[2 * r + 1] * Lg;
    }

    // hoisted zero C for the first MFMA of each chain
    const f32x4 zero4 = {0.f, 0.f, 0.f, 0.f};

    // zero both h-table buffers (2*4*80 shorts = 320 dwords)
    for (int i = tid; i < 320; i += THREADS)
        reinterpret_cast<unsigned*>(s_ht)[i] = 0;

    // ---- x: depth-4 prefetch in four NAMED regs (static rotation) ---------
    const float* xb = x + (b0 + bloc) * 2;
    float2 x0 = *reinterpret_cast<const float2*>(xb + 0 * BATCH * 2);
    float2 x1 = *reinterpret_cast<const float2*>(xb + 1 * BATCH * 2);
    float2 x2 = *reinterpret_cast<const float2*>(xb + 2 * BATCH * 2);
    float2 x3 = *reinterpret_cast<const float2*>(xb + 3 * BATCH * 2);

    __syncthreads();   // one full barrier (init visible)

    // ---- ANTIPHASE SKEW: second dispatch wave spins ~512 cyc once ---------
    if (blockIdx.x & 256) {
        asm volatile(
            "s_nop 7\n s_nop 7\n s_nop 7\n s_nop 7\n s_nop 7\n s_nop 7\n s_nop 7\n s_nop 7\n"
            "s_nop 7\n s_nop 7\n s_nop 7\n s_nop 7\n s_nop 7\n s_nop 7\n s_nop 7\n s_nop 7\n"
            "s_nop 7\n s_nop 7\n s_nop 7\n s_nop 7\n s_nop 7\n s_nop 7\n s_nop 7\n s_nop 7\n"
            "s_nop 7\n s_nop 7\n s_nop 7\n s_nop 7\n s_nop 7\n s_nop 7\n s_nop 7\n s_nop 7\n"
            "s_nop 7\n s_nop 7\n s_nop 7\n s_nop 7\n s_nop 7\n s_nop 7\n s_nop 7\n s_nop 7\n"
            "s_nop 7\n s_nop 7\n s_nop 7\n s_nop 7\n s_nop 7\n s_nop 7\n s_nop 7\n s_nop 7\n"
            "s_nop 7\n s_nop 7\n s_nop 7\n s_nop 7\n s_nop 7\n s_nop 7\n s_nop 7\n s_nop 7\n"
            "s_nop 7\n s_nop 7\n s_nop 7\n s_nop 7\n s_nop 7\n s_nop 7\n s_nop 7\n s_nop 7\n"
            ::: "memory");
    }

    // initial B fragments from buf 0 (h = 0); single b128 per kk
    bf16x8 Bf[2];
    #pragma unroll
    for (int kk = 0; kk < 2; ++kk)
        Bf[kk] = *reinterpret_cast<const bf16x8*>(
                     &s_ht[0][bloc * HSTR + kk * 32 + grp * 8]);

    // one LSTM step; XV is this sub-step's x slot (consumed then reloaded
    // with the value 4 steps ahead); P is the compile-time h-table parity.
#define LSTM_STEP(XV, P, SN)                                                   \
    {                                                                          \
        float gxL[4];                                                          \
        _Pragma("unroll")                                                      \
        for (int g = 0; g < 4; ++g)                                            \
            gxL[g] = fmaf(c1L[g], (XV).y, fmaf(c0L[g], (XV).x, gbL[g]));       \
        const int sn_ = ((SN) < T_STEPS) ? (SN) : T_STEPS - 1;                 \
        (XV) = *reinterpret_cast<const float2*>(xb + sn_ * BATCH * 2);         \
        f32x4 acc[4];                                                          \
        _Pragma("unroll")                                                      \
        for (int g = 0; g < 4; ++g)                                            \
            acc[g] = __builtin_amdgcn_mfma_f32_16x16x32_bf16(                  \
                         Af[g][0], Bf[0], zero4, 0, 0, 0);                     \
        _Pragma("unroll")                                                      \
        for (int g = 0; g < 4; ++g)                                            \
            acc[g] = __builtin_amdgcn_mfma_f32_16x16x32_bf16(                  \
                         Af[g][1], Bf[1], acc[g], 0, 0, 0);                    \
        __builtin_amdgcn_s_setprio(1);                                         \
        float pL[4];                                                           \
        _Pragma("unroll")                                                      \
        for (int g = 0; g < 4; ++g) {                                          \
            const float v01 = (eh & 1) ? acc[g][1] : acc[g][0];                \
            const float v23 = (eh & 1) ? acc[g][3] : acc[g][2];                \
            const float sel = (eh & 2) ? v23 : v01;                            \
            pL[g] = fmaf(sel, (g == 2) ? L2 : L1, gxL[g]);                     \
        }                                                                      \
        {                                                                      \
            const float ei = exp2_(pL[0]), ef = exp2_(pL[1]);                  \
            const float eg = exp2_(pL[2]), eo = exp2_(pL[3]);                  \
            const float ai = 1.f + ei, af = 1.f + ef;                          \
            const float ag = 1.f + eg, ao = 1.f + eo;                          \
            const float rif = rcp_(ai * af);                                   \
            const float si = rif * af, sf = rif * ai;                          \
            const float rgo = rcp_(ag * ao);                                   \
            const float tg = fmaf(-2.f, rgo * ao, 1.f);                        \
            const float so = rgo * ag;                                         \
            cs = fmaf(sf, cs, si * tg);                                        \
            const float ec = exp2_(cs * L2);                                   \
            hv = so * fmaf(-2.f, rcp_(1.f + ec), 1.f);                         \
        }                                                                      \
        s_ht[P][bloc * HSTR + rbase] = (unsigned short)bf16_rn(hv);            \
        __builtin_amdgcn_s_setprio(0);                                         \
        lds_barrier();                                                         \
        _Pragma("unroll")                                                      \
        for (int kk = 0; kk < 2; ++kk)                                         \
            Bf[kk] = *reinterpret_cast<const bf16x8*>(                         \
                         &s_ht[P][bloc * HSTR + kk * 32 + grp * 8]);           \
    }

    for (int s = 0; s < T_STEPS; s += 4) {
        LSTM_STEP(x0, 1, s + 4);
        LSTM_STEP(x1, 0, s + 5);
        LSTM_STEP(x2, 1, s + 6);
        LSTM_STEP(x3, 0, s + 7);
    }
#undef LSTM_STEP

    // ---- fused fc epilogue ----------------------------------------------
    float v = hv * wfc;
    v += __shfl_xor(v, 4);    // eh bit 0
    v += __shfl_xor(v, 8);    // eh bit 1
    v += __shfl_xor(v, 16);   // grp bit 0
    v += __shfl_xor(v, 32);   // grp bit 1
    if (lane < 4) s_red[w * 4 + lane] = v;   // one writer per (w, bloc)
    __syncthreads();
    if (tid < 4) {
        out[b0 + tid] = s_red[tid] + s_red[4 + tid] + s_red[8 + tid]
                      + s_red[12 + tid] + b_fc[0];
    }
}

extern "C" void kernel_launch(void* const* d_in, const int* in_sizes, int n_in,
                              void* d_out, int out_size, void* d_ws, size_t ws_size,
                              hipStream_t stream) {
    const float* x    = (const float*)d_in[0];
    const float* W_ih = (const float*)d_in[1];
    const float* W_hh = (const float*)d_in[2];
    const float* b_ih = (const float*)d_in[3];
    const float* b_hh = (const float*)d_in[4];
    const float* W_fc = (const float*)d_in[5];
    const float* b_fc = (const float*)d_in[6];
    float* out = (float*)d_out;

    dim3 grid(BATCH / BB);   // 512 blocks -> 2 independent blocks per CU
    dim3 block(THREADS);     // 4 waves
    lstm_mfma19<<<grid, block, 0, stream>>>(x, W_ih, W_hh, b_ih, b_hh, W_fc, b_fc, out);
}